// Round 7
// baseline (442.596 us; speedup 1.0000x reference)
//
#include <hip/hip_runtime.h>

typedef __bf16 bf16;
typedef __bf16 bf16x4 __attribute__((ext_vector_type(4)));
typedef __bf16 bf16x8 __attribute__((ext_vector_type(8)));
typedef float f32x4 __attribute__((ext_vector_type(4)));

#define NROWS 32768   // B*S = 32*1024
#define EMBED 512
#define CONV_C 512
#define HID 1024
#define LABELS 128

// swap low/high half-nibbles of a 4-bit value
__device__ inline int swap4(int x) { return ((x >> 2) | ((x & 3) << 2)) & 15; }
// swap bits 0 and 2 of a 4-bit value (involution)
__device__ inline int bitswap02(int g) {
  return ((g & 1) << 2) | (g & 0xA) | ((g >> 2) & 1);
}

__device__ inline bf16x8 cvt8r(f32x4 lo, f32x4 hi) {
  bf16x8 r;
  r[0] = (bf16)lo[0]; r[1] = (bf16)lo[1]; r[2] = (bf16)lo[2]; r[3] = (bf16)lo[3];
  r[4] = (bf16)hi[0]; r[5] = (bf16)hi[1]; r[6] = (bf16)hi[2]; r[7] = (bf16)hi[3];
  return r;
}

// ---- prep kernels ----------------------------------------------------------

__global__ void cvt_bf16(const float* __restrict__ in, bf16* __restrict__ out, int n) {
  int i = (blockIdx.x * blockDim.x + threadIdx.x) * 4;
  if (i >= n) return;
  float4 v = *(const float4*)(in + i);
  bf16x4 o;
  o.x = (bf16)v.x; o.y = (bf16)v.y; o.z = (bf16)v.z; o.w = (bf16)v.w;
  *(bf16x4*)(out + i) = o;
}

// [K,N] f32 -> [N,K] bf16 transpose, 64x64 tiles
__global__ void transpose_cvt(const float* __restrict__ in, bf16* __restrict__ out,
                              int K, int N) {
  __shared__ float t[64][65];
  int kb = blockIdx.x * 64, nb = blockIdx.y * 64;
  for (int i = threadIdx.x; i < 4096; i += 256) {
    int r = i >> 6, c = i & 63;
    t[r][c] = in[(size_t)(kb + r) * N + nb + c];
  }
  __syncthreads();
  for (int i = threadIdx.x; i < 4096; i += 256) {
    int r = i >> 6, c = i & 63;
    out[(size_t)(nb + r) * K + kb + c] = (bf16)t[c][r];
  }
}

// ---- layer 1: h = relu(emb[tok] @ conv_w^T + conv_b) -----------------------
// Register-streaming K-loop: NO LDS, NO barriers. A fragments gathered
// per-lane directly from emb (fp32, cvt in regs); B fragments directly from
// conv_w bf16. Explicit 1-step register double-buffer -> compiler pipelines
// with fine-grained vmcnt (AITER-style).
__global__ __launch_bounds__(256, 2) void gemm1_reg(
    const int* __restrict__ tok, const float* __restrict__ emb,
    const bf16* __restrict__ convw, const float* __restrict__ bias,
    bf16* __restrict__ out) {
  const int tid = threadIdx.x, wave = tid >> 6, lane = tid & 63;
  const int m0 = blockIdx.x * 128, n0 = blockIdx.y * 128;
  const int wm = (wave & 1) * 64, wn = (wave >> 1) * 64;
  const int lrow = lane & 15, quad = lane >> 4;

  const float* aptr[4];
  const bf16* bptr[4];
#pragma unroll
  for (int t = 0; t < 4; ++t) {
    int trow = tok[m0 + wm + t * 16 + lrow];
    aptr[t] = emb + (size_t)trow * EMBED + quad * 8;
    bptr[t] = convw + (size_t)(n0 + wn + t * 16 + lrow) * EMBED + quad * 8;
  }

  const f32x4 zero4 = {0.f, 0.f, 0.f, 0.f};
  f32x4 acc[4][4];
#pragma unroll
  for (int i = 0; i < 4; ++i)
#pragma unroll
    for (int j = 0; j < 4; ++j) acc[i][j] = zero4;

  f32x4 alo0[4], ahi0[4], alo1[4], ahi1[4];
  bf16x8 b0[4], b1[4];

#define LD1(alo, ahi, bb, k)                                   \
  {                                                            \
    _Pragma("unroll") for (int t = 0; t < 4; ++t) {            \
      alo[t] = *(const f32x4*)(aptr[t] + (k));                 \
      ahi[t] = *(const f32x4*)(aptr[t] + (k) + 4);             \
      bb[t] = *(const bf16x8*)(bptr[t] + (k));                 \
    }                                                          \
  }
#define STEP1(alo, ahi, bb)                                    \
  {                                                            \
    bf16x8 a[4];                                               \
    _Pragma("unroll") for (int t = 0; t < 4; ++t)              \
        a[t] = cvt8r(alo[t], ahi[t]);                          \
    _Pragma("unroll") for (int mi = 0; mi < 4; ++mi)           \
        _Pragma("unroll") for (int ni = 0; ni < 4; ++ni)       \
            acc[mi][ni] = __builtin_amdgcn_mfma_f32_16x16x32_bf16( \
                a[mi], bb[ni], acc[mi][ni], 0, 0, 0);          \
  }

  LD1(alo0, ahi0, b0, 0);
#pragma unroll
  for (int kk = 0; kk < 8; ++kk) {
    LD1(alo1, ahi1, b1, kk * 64 + 32);
    STEP1(alo0, ahi0, b0);
    if (kk < 7) LD1(alo0, ahi0, b0, kk * 64 + 64);
    STEP1(alo1, ahi1, b1);
  }
#undef LD1
#undef STEP1

#pragma unroll
  for (int mi = 0; mi < 4; ++mi) {
#pragma unroll
    for (int ni = 0; ni < 4; ++ni) {
      int col = n0 + wn + ni * 16 + lrow;
      float bv = bias[col];
#pragma unroll
      for (int r = 0; r < 4; ++r) {
        int row = m0 + wm + mi * 16 + quad * 4 + r;
        float v = acc[mi][ni][r] + bv;
        v = v > 0.f ? v : 0.f;
        out[(size_t)row * CONV_C + col] = (bf16)v;
      }
    }
  }
}

// ---- fused layers 2+3 (register-streaming; LDS only for z transpose) -------
// Per block: 64 rows. 8 hid-chunks of 128. Layer-2 K-loop: A (h rows) and
// B (w1t rows) loaded global->VGPR, register dbuf, NO barriers. Layer 3:
// b3 frags global from w2t; z round-trips through 16 KB swizzled zbuf
// (2 barriers per chunk).
__global__ __launch_bounds__(256, 2) void gemm23_reg(
    const bf16* __restrict__ h,     // [32768, 512]
    const bf16* __restrict__ w1t,   // [1024, 512]
    const bf16* __restrict__ w2t,   // [128, 1024]
    const float* __restrict__ b1, const float* __restrict__ b2,
    float* __restrict__ out) {
  __shared__ __attribute__((aligned(16))) bf16 zbuf[64 * 128];  // 16 KB
  const int tid = threadIdx.x, wave = tid >> 6, lane = tid & 63;
  const int m0 = blockIdx.x * 64;
  const int wm = (wave & 1) * 32, wn = (wave >> 1) * 64;
  const int lrow = lane & 15, quad = lane >> 4;
  const int sw_lrow = swap4(lrow);

  const bf16* aptr[2];
#pragma unroll
  for (int t = 0; t < 2; ++t)
    aptr[t] = h + (size_t)(m0 + wm + t * 16 + lrow) * 512 + quad * 8;
  // layer-3 B rows (labels) — constant across chunks
  const bf16* b3ptr[4];
#pragma unroll
  for (int t = 0; t < 4; ++t)
    b3ptr[t] = w2t + (size_t)(wn + t * 16 + lrow) * HID + quad * 8;

  const f32x4 zero4 = {0.f, 0.f, 0.f, 0.f};
  f32x4 out_acc[2][4];
#pragma unroll
  for (int i = 0; i < 2; ++i)
#pragma unroll
    for (int j = 0; j < 4; ++j) out_acc[i][j] = zero4;

  for (int chunk = 0; chunk < 8; ++chunk) {
    const bf16* bptr[4];
#pragma unroll
    for (int t = 0; t < 4; ++t)
      bptr[t] = w1t + (size_t)(chunk * 128 + wn + t * 16 + lrow) * 512 + quad * 8;

    f32x4 z_acc[2][4];
#pragma unroll
    for (int i = 0; i < 2; ++i)
#pragma unroll
      for (int j = 0; j < 4; ++j) z_acc[i][j] = zero4;

    bf16x8 a0[2], a1[2], b0[4], b1v[4];
#define LD2(aa, bb, k)                                         \
  {                                                            \
    _Pragma("unroll") for (int t = 0; t < 2; ++t)              \
        aa[t] = *(const bf16x8*)(aptr[t] + (k));               \
    _Pragma("unroll") for (int t = 0; t < 4; ++t)              \
        bb[t] = *(const bf16x8*)(bptr[t] + (k));               \
  }
#define STEP2(aa, bb)                                          \
  {                                                            \
    _Pragma("unroll") for (int mi = 0; mi < 2; ++mi)           \
        _Pragma("unroll") for (int ni = 0; ni < 4; ++ni)       \
            z_acc[mi][ni] = __builtin_amdgcn_mfma_f32_16x16x32_bf16( \
                aa[mi], bb[ni], z_acc[mi][ni], 0, 0, 0);       \
  }
    LD2(a0, b0, 0);
#pragma unroll
    for (int kk = 0; kk < 8; ++kk) {
      LD2(a1, b1v, kk * 64 + 32);
      STEP2(a0, b0);
      if (kk < 7) LD2(a0, b0, kk * 64 + 64);
      STEP2(a1, b1v);
    }
#undef LD2
#undef STEP2

    // write z (bias+relu, bf16) into swizzled zbuf
    // (first barrier: previous chunk's zbuf reads must be complete)
    __syncthreads();
#pragma unroll
    for (int mi = 0; mi < 2; ++mi) {
#pragma unroll
      for (int ni = 0; ni < 4; ++ni) {
        int col = wn + ni * 16 + lrow;
        float bv = b1[chunk * 128 + col];
        int gsw = bitswap02(col >> 3);
#pragma unroll
        for (int r = 0; r < 4; ++r) {
          int row = wm + mi * 16 + quad * 4 + r;
          float v = z_acc[mi][ni][r] + bv;
          v = v > 0.f ? v : 0.f;
          int pos = gsw ^ (quad | (r << 2));  // swap4(quad*4+r)
          zbuf[row * 128 + pos * 8 + (col & 7)] = (bf16)v;
        }
      }
    }
    // layer-3 B fragments direct from global (L2-hot), latency covered by
    // the zbuf writes + barrier below
    bf16x8 b3[4][4];
#pragma unroll
    for (int ni = 0; ni < 4; ++ni)
#pragma unroll
      for (int ks = 0; ks < 4; ++ks)
        b3[ni][ks] = *(const bf16x8*)(b3ptr[ni] + chunk * 128 + ks * 32);
    __syncthreads();

    // out_acc += z_chunk @ w2t_chunk^T (K=128)
#pragma unroll
    for (int ks = 0; ks < 4; ++ks) {
      int possw = bitswap02(ks * 4 + quad) ^ sw_lrow;
      bf16x8 a3[2];
#pragma unroll
      for (int mi = 0; mi < 2; ++mi) {
        int row = wm + mi * 16 + lrow;
        a3[mi] = *(const bf16x8*)(zbuf + row * 128 + possw * 8);
      }
#pragma unroll
      for (int mi = 0; mi < 2; ++mi)
#pragma unroll
        for (int ni = 0; ni < 4; ++ni)
          out_acc[mi][ni] = __builtin_amdgcn_mfma_f32_16x16x32_bf16(
              a3[mi], b3[ni][ks], out_acc[mi][ni], 0, 0, 0);
    }
  }

  // epilogue: out = out_acc + b2
#pragma unroll
  for (int mi = 0; mi < 2; ++mi) {
#pragma unroll
    for (int ni = 0; ni < 4; ++ni) {
      int col = wn + ni * 16 + lrow;
      float bv = b2[col];
#pragma unroll
      for (int r = 0; r < 4; ++r) {
        int row = m0 + wm + mi * 16 + quad * 4 + r;
        out[(size_t)row * LABELS + col] = out_acc[mi][ni][r] + bv;
      }
    }
  }
}

// ---- launcher --------------------------------------------------------------

extern "C" void kernel_launch(void* const* d_in, const int* in_sizes, int n_in,
                              void* d_out, int out_size, void* d_ws, size_t ws_size,
                              hipStream_t stream) {
  const int* tok = (const int*)d_in[0];
  const float* emb = (const float*)d_in[1];
  const float* conv_w = (const float*)d_in[2];  // [512,512] = [N,K]
  const float* conv_b = (const float*)d_in[3];
  const float* w1 = (const float*)d_in[4];      // [512,1024] = [K,N]
  const float* b1 = (const float*)d_in[5];
  const float* w2 = (const float*)d_in[6];      // [1024,128] = [K,N]
  const float* b2 = (const float*)d_in[7];
  float* out = (float*)d_out;

  char* ws = (char*)d_ws;
  bf16* wtc = (bf16*)(ws);                       // 512 KB [512,512]
  bf16* wt1 = (bf16*)(ws + (1u << 19));          // 1 MB   [1024,512]
  bf16* wt2 = (bf16*)(ws + 3 * (1u << 19));      // 256 KB [128,1024]
  bf16* h = (bf16*)(ws + (2u << 20));            // 32 MB  [32768,512]

  // weight prep
  hipLaunchKernelGGL(cvt_bf16, dim3(256), dim3(256), 0, stream,
                     conv_w, wtc, CONV_C * EMBED);
  hipLaunchKernelGGL(transpose_cvt, dim3(8, 16), dim3(256), 0, stream,
                     w1, wt1, CONV_C, HID);
  hipLaunchKernelGGL(transpose_cvt, dim3(16, 2), dim3(256), 0, stream,
                     w2, wt2, HID, LABELS);

  // layer 1 (register-streaming, gather fused)
  hipLaunchKernelGGL(gemm1_reg, dim3(NROWS / 128, CONV_C / 128), dim3(256),
                     0, stream, tok, emb, wtc, conv_b, h);
  // layers 2+3 fused (register-streaming)
  hipLaunchKernelGGL(gemm23_reg, dim3(NROWS / 64), dim3(256),
                     0, stream, h, wt1, wt2, b1, b2, out);
}